// Round 1
// baseline (290.354 us; speedup 1.0000x reference)
//
#include <hip/hip_runtime.h>

// Problem constants (from reference): B=64, J=32, M=160, N=160
#define BB 64
#define JJ 32
#define MM 160
#define NN 160
#define MNV (MM * NN)          // 25600 floats per (b,j) map
#define MNV4 (MNV / 4)         // 6400 float4

__global__ void zero_out_kernel(float* __restrict__ out) {
    out[threadIdx.x] = 0.0f;   // out_size == 64 == blockDim
}

__global__ __launch_bounds__(256) void label_loss_kernel(
    const float* __restrict__ pred,    // (B, 9, J, 1)
    const float* __restrict__ gt,      // (B, J, 11)
    const float* __restrict__ heatmap, // (B, J, M, N)
    float* __restrict__ out)           // (B,)
{
    const int bj = blockIdx.x;         // 0 .. B*J-1
    const int b  = bj / JJ;
    const int j  = bj % JJ;
    const int tid = threadIdx.x;

    const float4* __restrict__ hm4 =
        (const float4*)(heatmap + (size_t)bj * MNV);

    // ---- per-thread argmax over this (b,j) map ----
    float best    = -INFINITY;
    int   bestIdx = 0;
    // ascending traversal + strict '>' keeps the FIRST occurrence per thread
    #pragma unroll 5
    for (int i = tid; i < MNV4; i += 256) {
        float4 v = hm4[i];
        int base = i << 2;
        if (v.x > best) { best = v.x; bestIdx = base;     }
        if (v.y > best) { best = v.y; bestIdx = base + 1; }
        if (v.z > best) { best = v.z; bestIdx = base + 2; }
        if (v.w > best) { best = v.w; bestIdx = base + 3; }
    }

    // ---- wave (64-lane) reduction with lowest-index tie-break ----
    #pragma unroll
    for (int off = 32; off > 0; off >>= 1) {
        float ov = __shfl_down(best,    off, 64);
        int   oi = __shfl_down(bestIdx, off, 64);
        if (ov > best || (ov == best && oi < bestIdx)) {
            best = ov; bestIdx = oi;
        }
    }

    // ---- cross-wave reduction (4 waves per block) ----
    __shared__ float svals[4];
    __shared__ int   sidxs[4];
    const int wave = tid >> 6;
    if ((tid & 63) == 0) { svals[wave] = best; sidxs[wave] = bestIdx; }
    __syncthreads();

    if (tid == 0) {
        #pragma unroll
        for (int w = 1; w < 4; ++w) {
            float ov = svals[w];
            int   oi = sidxs[w];
            if (ov > best || (ov == best && oi < bestIdx)) {
                best = ov; bestIdx = oi;
            }
        }

        // x = idx // M ; y = idx % M   (M == N == 160, row-major M*N flatten)
        const float x = (float)(bestIdx / MM);
        const float y = (float)(bestIdx % MM);

        const float* __restrict__ g = gt + (size_t)bj * 11;
        const float g9  = g[9];
        const float g10 = g[10];
        const bool valid = (g9 > 0.0f) && (g10 > 0.0f) &&
                           (g9 < (float)MM) && (g10 < (float)NN);

        float loss = 0.0f;
        if (valid) {
            // pred[b][c][j][0] = pred[(b*9 + c)*J + j]
            const float* __restrict__ p = pred + ((size_t)b * 9) * JJ + j;
            float cls = 0.0f;
            #pragma unroll
            for (int k = 0; k < 7; ++k) {
                float d = p[k * JJ] - g[k];
                cls += d * d;
            }
            const float px = p[7 * JJ];
            const float py = p[8 * JJ];
            const float dx = g9  + g[7] - x - px;
            const float dy = g10 + g[8] - y - py;
            loss = cls + dx * dx + dy * dy;
        }
        atomicAdd(&out[b], loss);
    }
}

extern "C" void kernel_launch(void* const* d_in, const int* in_sizes, int n_in,
                              void* d_out, int out_size, void* d_ws, size_t ws_size,
                              hipStream_t stream) {
    const float* pred    = (const float*)d_in[0];
    const float* gt      = (const float*)d_in[1];
    const float* heatmap = (const float*)d_in[2];
    float* out = (float*)d_out;

    // d_out is re-poisoned to 0xAA before every launch -> zero it first
    zero_out_kernel<<<1, BB, 0, stream>>>(out);

    label_loss_kernel<<<BB * JJ, 256, 0, stream>>>(pred, gt, heatmap, out);
}

// Round 2
// 288.905 us; speedup vs baseline: 1.0050x; 1.0050x over previous
//
#include <hip/hip_runtime.h>

// Problem constants (from reference): B=64, J=32, M=160, N=160
#define BB 64
#define JJ 32
#define MM 160
#define NN 160
#define MNV (MM * NN)          // 25600 floats per (b,j) map
#define MNV4 (MNV / 4)         // 6400 float4

// Phase 1: one block per (b,j). Argmax over the 160x160 map + per-object
// loss, written to ws[bj]. No atomics, no pre-zero needed.
__global__ __launch_bounds__(256) void label_loss_kernel(
    const float* __restrict__ pred,    // (B, 9, J, 1)
    const float* __restrict__ gt,      // (B, J, 11)
    const float* __restrict__ heatmap, // (B, J, M, N)
    float* __restrict__ ws)            // (B*J,) per-object losses
{
    const int bj = blockIdx.x;         // 0 .. B*J-1
    const int b  = bj / JJ;
    const int j  = bj % JJ;
    const int tid = threadIdx.x;

    const float4* __restrict__ hm4 =
        (const float4*)(heatmap + (size_t)bj * MNV);

    // ---- per-thread argmax: 4 INDEPENDENT chains (one per float4 lane) ----
    // Ascending traversal + strict '>' keeps the first occurrence per chain.
    float bv0 = -INFINITY, bv1 = -INFINITY, bv2 = -INFINITY, bv3 = -INFINITY;
    int   bi0 = 0, bi1 = 0, bi2 = 0, bi3 = 0;
    #pragma unroll 5
    for (int i = tid; i < MNV4; i += 256) {
        float4 v = hm4[i];
        int base = i << 2;
        if (v.x > bv0) { bv0 = v.x; bi0 = base;     }
        if (v.y > bv1) { bv1 = v.y; bi1 = base + 1; }
        if (v.z > bv2) { bv2 = v.z; bi2 = base + 2; }
        if (v.w > bv3) { bv3 = v.w; bi3 = base + 3; }
    }

    // merge the 4 chains (lowest-index tie-break => first occurrence)
    float best = bv0; int bestIdx = bi0;
    if (bv1 > best || (bv1 == best && bi1 < bestIdx)) { best = bv1; bestIdx = bi1; }
    if (bv2 > best || (bv2 == best && bi2 < bestIdx)) { best = bv2; bestIdx = bi2; }
    if (bv3 > best || (bv3 == best && bi3 < bestIdx)) { best = bv3; bestIdx = bi3; }

    // ---- wave (64-lane) reduction with lowest-index tie-break ----
    #pragma unroll
    for (int off = 32; off > 0; off >>= 1) {
        float ov = __shfl_down(best,    off, 64);
        int   oi = __shfl_down(bestIdx, off, 64);
        if (ov > best || (ov == best && oi < bestIdx)) {
            best = ov; bestIdx = oi;
        }
    }

    // ---- cross-wave reduction (4 waves per block) ----
    __shared__ float svals[4];
    __shared__ int   sidxs[4];
    const int wave = tid >> 6;
    if ((tid & 63) == 0) { svals[wave] = best; sidxs[wave] = bestIdx; }
    __syncthreads();

    if (tid == 0) {
        #pragma unroll
        for (int w = 1; w < 4; ++w) {
            float ov = svals[w];
            int   oi = sidxs[w];
            if (ov > best || (ov == best && oi < bestIdx)) {
                best = ov; bestIdx = oi;
            }
        }

        // x = idx // M ; y = idx % M   (row-major M*N flatten, M==N==160)
        const float x = (float)(bestIdx / MM);
        const float y = (float)(bestIdx % MM);

        const float* __restrict__ g = gt + (size_t)bj * 11;
        const float g9  = g[9];
        const float g10 = g[10];
        const bool valid = (g9 > 0.0f) && (g10 > 0.0f) &&
                           (g9 < (float)MM) && (g10 < (float)NN);

        float loss = 0.0f;
        if (valid) {
            // pred[b][c][j][0] = pred[(b*9 + c)*J + j]
            const float* __restrict__ p = pred + ((size_t)b * 9) * JJ + j;
            float cls = 0.0f;
            #pragma unroll
            for (int k = 0; k < 7; ++k) {
                float d = p[k * JJ] - g[k];
                cls += d * d;
            }
            const float px = p[7 * JJ];
            const float py = p[8 * JJ];
            const float dx = g9  + g[7] - x - px;
            const float dy = g10 + g[8] - y - py;
            loss = cls + dx * dx + dy * dy;
        }
        ws[bj] = loss;
    }
}

// Phase 2: one wave; thread b sums its 32 contiguous per-object losses.
// Writes ALL 64 outputs -> no zero-init of d_out needed.
__global__ __launch_bounds__(64) void reduce_kernel(
    const float* __restrict__ ws, float* __restrict__ out)
{
    const int b = threadIdx.x;   // 0..63
    const float4* __restrict__ w4 = (const float4*)(ws + b * JJ);
    float s = 0.0f;
    #pragma unroll
    for (int k = 0; k < JJ / 4; ++k) {
        float4 v = w4[k];
        s += v.x + v.y + v.z + v.w;
    }
    out[b] = s;
}

extern "C" void kernel_launch(void* const* d_in, const int* in_sizes, int n_in,
                              void* d_out, int out_size, void* d_ws, size_t ws_size,
                              hipStream_t stream) {
    const float* pred    = (const float*)d_in[0];
    const float* gt      = (const float*)d_in[1];
    const float* heatmap = (const float*)d_in[2];
    float* ws  = (float*)d_ws;
    float* out = (float*)d_out;

    label_loss_kernel<<<BB * JJ, 256, 0, stream>>>(pred, gt, heatmap, ws);
    reduce_kernel<<<1, BB, 0, stream>>>(ws, out);
}